// Round 5
// baseline (318.976 us; speedup 1.0000x reference)
//
#include <hip/hip_runtime.h>

#define NB     32
#define NKEYS  2048
#define D      512
#define NCHUNK 64
#define RPC    (NKEYS / NCHUNK)    // 32 rows per chunk

__device__ __forceinline__ float wave_sum(float v) {
    #pragma unroll
    for (int o = 32; o > 0; o >>= 1) v += __shfl_xor(v, o);
    return v;
}

// blocks 0..511: wkh[dk] = Wk[dk,:]·Wh ; and scatter Q[b,dk]*wqh[dk] -> qacc[b]
// block 512:     cbias = (bk+bq)·Wh + bh
__global__ __launch_bounds__(256) void prep_kernel(const float* __restrict__ Wk,
        const float* __restrict__ Wq, const float* __restrict__ Wh,
        const float* __restrict__ Q, const float* __restrict__ bk,
        const float* __restrict__ bq, const float* __restrict__ bh,
        float* __restrict__ wkh, float* __restrict__ qacc, float* __restrict__ cbias) {
    int tid = threadIdx.x, lane = tid & 63, wv = tid >> 6;
    __shared__ float sred[8];
    if (blockIdx.x < D) {
        int dk = blockIdx.x;
        float sk = 0.f, sq = 0.f;
        #pragma unroll
        for (int h = tid; h < D; h += 256) {
            float wh = Wh[h];
            sk = fmaf(Wk[dk * D + h], wh, sk);
            sq = fmaf(Wq[dk * D + h], wh, sq);
        }
        sk = wave_sum(sk); sq = wave_sum(sq);
        if (lane == 0) { sred[wv] = sk; sred[wv + 4] = sq; }
        __syncthreads();
        if (tid == 0) wkh[dk] = sred[0] + sred[1] + sred[2] + sred[3];
        float sqt = sred[4] + sred[5] + sred[6] + sred[7];   // wqh[dk]
        if (tid < NB) atomicAdd(&qacc[tid], Q[tid * D + dk] * sqt);
    } else {
        float s = 0.f;
        #pragma unroll
        for (int h = tid; h < D; h += 256) s = fmaf(bk[h] + bq[h], Wh[h], s);
        s = wave_sum(s);
        if (lane == 0) sred[wv] = s;
        __syncthreads();
        if (tid == 0) cbias[0] = sred[0] + sred[1] + sred[2] + sred[3] + bh[0];
    }
}

// p[b,n] = exp(relu(K[b,n,:]·wkh + qacc[b] + cbias))  — one wave per K-row.
// Pure K stream. grid: (NB*NKEYS)/4 = 16384 blocks x 256 threads.
__global__ __launch_bounds__(256) void energy_kernel(const float* __restrict__ K,
        const float* __restrict__ wkh, const float* __restrict__ qacc,
        const float* __restrict__ cbias, float* __restrict__ p) {
    int tid  = threadIdx.x;
    int lane = tid & 63, wv = tid >> 6;
    long row = (long)blockIdx.x * 4 + wv;           // 0 .. 65535
    int b = (int)(row >> 11);
    float qd = qacc[b] + cbias[0];                  // L2-hot scalars
    const float4* kr = (const float4*)(K + row * D);
    const float4* wr = (const float4*)wkh;
    float4 k0 = kr[lane],      w0 = wr[lane];
    float4 k1 = kr[lane + 64], w1 = wr[lane + 64];
    float s = k0.x * w0.x + k0.y * w0.y + k0.z * w0.z + k0.w * w0.w
            + k1.x * w1.x + k1.y * w1.y + k1.z * w1.z + k1.w * w1.w;
    s = wave_sum(s);
    // relu bounds energies; exp without max-shift is fp32-safe and cancels
    // identically after normalization.
    if (lane == 0) p[row] = expf(fmaxf(s + qd, 0.f));
}

// partial[b,chunk,v] = sum_{r} p[b,n0+r] * V[b,n0+r,v]; last block per batch
// (device-scope counter) finalizes: S=sum p, wout=p/S, out=(sum_c partial)/S.
// grid: NB*NCHUNK = 2048 blocks x 256 threads.
__global__ __launch_bounds__(256) void weightedv_kernel(const float* __restrict__ V,
        const float* __restrict__ p, float* __restrict__ partial,
        int* __restrict__ cnt, float* __restrict__ out, float* __restrict__ wout) {
    int chunk = blockIdx.x & (NCHUNK - 1);
    int b     = blockIdx.x >> 6;
    int tid   = threadIdx.x;
    int n0    = chunk * RPC;
    const float* pb = p + b * NKEYS + n0;
    float pw[RPC];
    #pragma unroll
    for (int r = 0; r < RPC; ++r) pw[r] = pb[r];    // uniform -> scalar loads
    const float2* vb = (const float2*)(V + ((long)b * NKEYS + n0) * D);
    float2 acc = {0.f, 0.f};
    #pragma unroll 8
    for (int r = 0; r < RPC; ++r) {
        float2 vv = vb[r * (D / 2) + tid];
        acc.x = fmaf(pw[r], vv.x, acc.x);
        acc.y = fmaf(pw[r], vv.y, acc.y);
    }
    ((float2*)(partial + (long)blockIdx.x * D))[tid] = acc;

    // ---- last-block-per-batch finalize ----
    __shared__ int amLast;
    __threadfence();                                 // release partial write
    if (tid == 0) amLast = (atomicAdd(&cnt[b], 1) == NCHUNK - 1);
    __syncthreads();
    if (!amLast) return;
    __threadfence();                                 // acquire others' partials

    int lane = tid & 63, wv = tid >> 6;
    const float4* p4 = (const float4*)(p + b * NKEYS);
    float4 v0 = p4[tid], v1 = p4[tid + 256];
    float s = v0.x + v0.y + v0.z + v0.w + v1.x + v1.y + v1.z + v1.w;
    s = wave_sum(s);
    __shared__ float sred[4];
    if (lane == 0) sred[wv] = s;
    __syncthreads();
    float inv = 1.f / (sred[0] + sred[1] + sred[2] + sred[3]);

    float4* wo = (float4*)(wout + b * NKEYS);
    v0.x *= inv; v0.y *= inv; v0.z *= inv; v0.w *= inv;
    v1.x *= inv; v1.y *= inv; v1.z *= inv; v1.w *= inv;
    wo[tid] = v0;
    wo[tid + 256] = v1;

    const float2* yb = (const float2*)(partial + (long)b * NCHUNK * D);
    float2 a2 = {0.f, 0.f};
    #pragma unroll
    for (int c = 0; c < NCHUNK; ++c) {
        float2 vv = yb[c * (D / 2) + tid];
        a2.x += vv.x;
        a2.y += vv.y;
    }
    a2.x *= inv; a2.y *= inv;
    ((float2*)(out + b * D))[tid] = a2;
}

extern "C" void kernel_launch(void* const* d_in, const int* in_sizes, int n_in,
                              void* d_out, int out_size, void* d_ws, size_t ws_size,
                              hipStream_t stream) {
    const float* Q  = (const float*)d_in[0];
    const float* K  = (const float*)d_in[1];
    const float* V  = (const float*)d_in[2];
    const float* Wk = (const float*)d_in[3];
    const float* bk = (const float*)d_in[4];
    const float* Wq = (const float*)d_in[5];
    const float* bq = (const float*)d_in[6];
    const float* Wh = (const float*)d_in[7];
    const float* bh = (const float*)d_in[8];

    float* out  = (float*)d_out;               // [32, 512]
    float* wout = out + NB * D;                // [32, 2048]

    float* ws      = (float*)d_ws;
    float* qacc    = ws;                       // 32 floats
    int*   cnt     = (int*)(ws + 32);          // 32 ints
    float* cbias   = ws + 64;                  // 1 (padded to 128)
    float* wkh     = ws + 128;                 // 512
    float* pbuf    = ws + 640;                 // 65536 (16B-aligned: 640*4=2560)
    float* partial = pbuf + NB * NKEYS;        // 32*64*512 = 1048576

    hipMemsetAsync(ws, 0, 64 * sizeof(float), stream);   // qacc + cnt
    prep_kernel<<<D + 1, 256, 0, stream>>>(Wk, Wq, Wh, Q, bk, bq, bh, wkh, qacc, cbias);
    energy_kernel<<<(NB * NKEYS) / 4, 256, 0, stream>>>(K, wkh, qacc, cbias, pbuf);
    weightedv_kernel<<<NB * NCHUNK, 256, 0, stream>>>(V, pbuf, partial, cnt, out, wout);
}

// Round 6
// 202.312 us; speedup vs baseline: 1.5767x; 1.5767x over previous
//
#include <hip/hip_runtime.h>

#define NB     32
#define NKEYS  2048
#define D      512
#define NCHUNK 64
#define RPC    (NKEYS / NCHUNK)    // 32 rows per chunk

__device__ __forceinline__ float wave_sum(float v) {
    #pragma unroll
    for (int o = 32; o > 0; o >>= 1) v += __shfl_xor(v, o);
    return v;
}

// blocks 0..511: wkh[dk] = Wk[dk,:]·Wh ; scatter Q[b,dk]*wqh[dk] -> qacc[b] (atomic)
// block 512:     cbias = (bk+bq)·Wh + bh
__global__ __launch_bounds__(256) void prep_kernel(const float* __restrict__ Wk,
        const float* __restrict__ Wq, const float* __restrict__ Wh,
        const float* __restrict__ Q, const float* __restrict__ bk,
        const float* __restrict__ bq, const float* __restrict__ bh,
        float* __restrict__ wkh, float* __restrict__ qacc, float* __restrict__ cbias) {
    int tid = threadIdx.x, lane = tid & 63, wv = tid >> 6;
    __shared__ float sred[8];
    if (blockIdx.x < D) {
        int dk = blockIdx.x;
        float sk = 0.f, sq = 0.f;
        #pragma unroll
        for (int h = tid; h < D; h += 256) {
            float wh = Wh[h];
            sk = fmaf(Wk[dk * D + h], wh, sk);
            sq = fmaf(Wq[dk * D + h], wh, sq);
        }
        sk = wave_sum(sk); sq = wave_sum(sq);
        if (lane == 0) { sred[wv] = sk; sred[wv + 4] = sq; }
        __syncthreads();
        if (tid == 0) wkh[dk] = sred[0] + sred[1] + sred[2] + sred[3];
        float sqt = sred[4] + sred[5] + sred[6] + sred[7];   // wqh[dk]
        if (tid < NB) atomicAdd(&qacc[tid], Q[tid * D + dk] * sqt);
    } else {
        float s = 0.f;
        #pragma unroll
        for (int h = tid; h < D; h += 256) s = fmaf(bk[h] + bq[h], Wh[h], s);
        s = wave_sum(s);
        if (lane == 0) sred[wv] = s;
        __syncthreads();
        if (tid == 0) cbias[0] = sred[0] + sred[1] + sred[2] + sred[3] + bh[0];
    }
}

// p[b,n] = exp(relu(K[b,n,:]·wkh + qacc[b] + cbias)); block-reduced atomicAdd
// into sacc[b]; blocks 0..63 also zero the 64KB output accumulator.
// Pure K stream. grid: (NB*NKEYS)/4 = 16384 blocks x 256 threads.
__global__ __launch_bounds__(256) void energy_kernel(const float* __restrict__ K,
        const float* __restrict__ wkh, const float* __restrict__ qacc,
        const float* __restrict__ cbias, float* __restrict__ p,
        float* __restrict__ sacc, float* __restrict__ outz) {
    int tid  = threadIdx.x;
    int lane = tid & 63, wv = tid >> 6;
    long row = (long)blockIdx.x * 4 + wv;           // 0 .. 65535 (no batch straddle)
    int b = (int)(row >> 11);
    float qd = qacc[b] + cbias[0];                  // L2-hot scalars
    const float4* kr = (const float4*)(K + row * D);
    const float4* wr = (const float4*)wkh;
    float4 k0 = kr[lane],      w0 = wr[lane];
    float4 k1 = kr[lane + 64], w1 = wr[lane + 64];
    float s = k0.x * w0.x + k0.y * w0.y + k0.z * w0.z + k0.w * w0.w
            + k1.x * w1.x + k1.y * w1.y + k1.z * w1.z + k1.w * w1.w;
    s = wave_sum(s);
    // relu bounds energies; exp without max-shift is fp32-safe and cancels
    // identically after normalization.
    float pv = expf(fmaxf(s + qd, 0.f));
    __shared__ float sp[4];
    if (lane == 0) { p[row] = pv; sp[wv] = pv; }
    if (blockIdx.x < (NB * D) / 256)                // zero out-accumulator
        outz[blockIdx.x * 256 + tid] = 0.f;
    __syncthreads();
    if (tid == 0) atomicAdd(&sacc[b], sp[0] + sp[1] + sp[2] + sp[3]);
}

// Per (b,chunk): normalized weighted-V accumulation straight into out (atomic),
// plus the chunk's 32 normalized weights. Pure V stream, no fences.
// grid: NB*NCHUNK = 2048 blocks x 256 threads.
__global__ __launch_bounds__(256) void weightedv_kernel(const float* __restrict__ V,
        const float* __restrict__ p, const float* __restrict__ sacc,
        float* __restrict__ out, float* __restrict__ wout) {
    int chunk = blockIdx.x & (NCHUNK - 1);
    int b     = blockIdx.x >> 6;
    int tid   = threadIdx.x;
    int n0    = chunk * RPC;
    float inv = 1.f / sacc[b];
    const float* pb = p + b * NKEYS + n0;
    float pw[RPC];
    #pragma unroll
    for (int r = 0; r < RPC; ++r) pw[r] = pb[r];    // uniform -> scalar regs
    const float2* vb = (const float2*)(V + ((long)b * NKEYS + n0) * D);
    float2 acc = {0.f, 0.f};
    #pragma unroll 8
    for (int r = 0; r < RPC; ++r) {
        float2 vv = vb[r * (D / 2) + tid];
        acc.x = fmaf(pw[r], vv.x, acc.x);
        acc.y = fmaf(pw[r], vv.y, acc.y);
    }
    acc.x *= inv; acc.y *= inv;
    atomicAdd(&out[b * D + 2 * tid],     acc.x);
    atomicAdd(&out[b * D + 2 * tid + 1], acc.y);
    if (tid < RPC) wout[b * NKEYS + n0 + tid] = pb[tid] * inv;  // fresh L2-hot load
}

extern "C" void kernel_launch(void* const* d_in, const int* in_sizes, int n_in,
                              void* d_out, int out_size, void* d_ws, size_t ws_size,
                              hipStream_t stream) {
    const float* Q  = (const float*)d_in[0];
    const float* K  = (const float*)d_in[1];
    const float* V  = (const float*)d_in[2];
    const float* Wk = (const float*)d_in[3];
    const float* bk = (const float*)d_in[4];
    const float* Wq = (const float*)d_in[5];
    const float* bq = (const float*)d_in[6];
    const float* Wh = (const float*)d_in[7];
    const float* bh = (const float*)d_in[8];

    float* out  = (float*)d_out;               // [32, 512]
    float* wout = out + NB * D;                // [32, 2048]

    float* ws    = (float*)d_ws;
    float* qacc  = ws;                         // 32
    float* sacc  = ws + 32;                    // 32
    float* cbias = ws + 64;                    // 1 (padded to 128)
    float* wkh   = ws + 128;                   // 512
    float* pbuf  = ws + 640;                   // 65536 (16B aligned)

    hipMemsetAsync(ws, 0, 64 * sizeof(float), stream);   // qacc + sacc
    prep_kernel<<<D + 1, 256, 0, stream>>>(Wk, Wq, Wh, Q, bk, bq, bh, wkh, qacc, cbias);
    energy_kernel<<<(NB * NKEYS) / 4, 256, 0, stream>>>(K, wkh, qacc, cbias, pbuf, sacc, out);
    weightedv_kernel<<<NB * NCHUNK, 256, 0, stream>>>(V, pbuf, sacc, out, wout);
}

// Round 7
// 63.518 us; speedup vs baseline: 5.0218x; 3.1851x over previous
//
#include <hip/hip_runtime.h>

#define NB     32
#define NKEYS  2048
#define D      512
#define NCHUNK 64
#define RPC    (NKEYS / NCHUNK)    // 32 rows per chunk

__device__ __forceinline__ float wave_sum(float v) {
    #pragma unroll
    for (int o = 32; o > 0; o >>= 1) v += __shfl_xor(v, o);
    return v;
}

// blocks 0..511: wkh[dk] = Wk[dk,:]·Wh ; scatter Q[b,dk]*wqh[dk] -> qacc[b] (atomic)
// block 512:     cbias = (bk+bq)·Wh + bh
__global__ __launch_bounds__(256) void prep_kernel(const float* __restrict__ Wk,
        const float* __restrict__ Wq, const float* __restrict__ Wh,
        const float* __restrict__ Q, const float* __restrict__ bk,
        const float* __restrict__ bq, const float* __restrict__ bh,
        float* __restrict__ wkh, float* __restrict__ qacc, float* __restrict__ cbias) {
    int tid = threadIdx.x, lane = tid & 63, wv = tid >> 6;
    __shared__ float sred[8];
    if (blockIdx.x < D) {
        int dk = blockIdx.x;
        float sk = 0.f, sq = 0.f;
        #pragma unroll
        for (int h = tid; h < D; h += 256) {
            float wh = Wh[h];
            sk = fmaf(Wk[dk * D + h], wh, sk);
            sq = fmaf(Wq[dk * D + h], wh, sq);
        }
        sk = wave_sum(sk); sq = wave_sum(sq);
        if (lane == 0) { sred[wv] = sk; sred[wv + 4] = sq; }
        __syncthreads();
        if (tid == 0) wkh[dk] = sred[0] + sred[1] + sred[2] + sred[3];
        float sqt = sred[4] + sred[5] + sred[6] + sred[7];   // wqh[dk]
        if (tid < NB) atomicAdd(&qacc[tid], Q[tid * D + dk] * sqt);
    } else {
        float s = 0.f;
        #pragma unroll
        for (int h = tid; h < D; h += 256) s = fmaf(bk[h] + bq[h], Wh[h], s);
        s = wave_sum(s);
        if (lane == 0) sred[wv] = s;
        __syncthreads();
        if (tid == 0) cbias[0] = sred[0] + sred[1] + sred[2] + sred[3] + bh[0];
    }
}

// p[b,n] = exp(relu(K[b,n,:]·wkh + qacc[b] + cbias))  — one wave per K-row.
// Blocks 0..63 also zero the 64KB output accumulator (independent, no sync).
// Pure K stream, no atomics. grid: (NB*NKEYS)/4 = 16384 blocks x 256 threads.
__global__ __launch_bounds__(256) void energy_kernel(const float* __restrict__ K,
        const float* __restrict__ wkh, const float* __restrict__ qacc,
        const float* __restrict__ cbias, float* __restrict__ p,
        float* __restrict__ outz) {
    int tid  = threadIdx.x;
    int lane = tid & 63, wv = tid >> 6;
    long row = (long)blockIdx.x * 4 + wv;           // 0 .. 65535
    int b = (int)(row >> 11);
    float qd = qacc[b] + cbias[0];                  // L2-hot scalars
    const float4* kr = (const float4*)(K + row * D);
    const float4* wr = (const float4*)wkh;
    float4 k0 = kr[lane],      w0 = wr[lane];
    float4 k1 = kr[lane + 64], w1 = wr[lane + 64];
    float s = k0.x * w0.x + k0.y * w0.y + k0.z * w0.z + k0.w * w0.w
            + k1.x * w1.x + k1.y * w1.y + k1.z * w1.z + k1.w * w1.w;
    s = wave_sum(s);
    // relu bounds energies; exp without max-shift is fp32-safe and cancels
    // identically after normalization.
    if (lane == 0) p[row] = expf(fmaxf(s + qd, 0.f));
    if (blockIdx.x < (NB * D) / 256)
        outz[blockIdx.x * 256 + tid] = 0.f;
}

// Per (b,chunk): S_b = sum(p[b,:]) computed per-block from L2-hot p (8KB),
// then normalized weighted-V accumulation into out (atomic, disjoint-ish
// addresses) and the chunk's 32 normalized weights. Pure V stream, no fences.
// grid: NB*NCHUNK = 2048 blocks x 256 threads.
__global__ __launch_bounds__(256) void weightedv_kernel(const float* __restrict__ V,
        const float* __restrict__ p, float* __restrict__ out,
        float* __restrict__ wout) {
    int chunk = blockIdx.x & (NCHUNK - 1);
    int b     = blockIdx.x >> 6;
    int tid   = threadIdx.x;
    int lane  = tid & 63, wv = tid >> 6;
    int n0    = chunk * RPC;

    // per-block S_b from cache-hot p
    const float4* pall = (const float4*)(p + b * NKEYS);
    float s = 0.f;
    #pragma unroll
    for (int i = 0; i < 2; ++i) {
        float4 v = pall[tid + i * 256];
        s += v.x + v.y + v.z + v.w;
    }
    s = wave_sum(s);
    __shared__ float sred[4];
    if (lane == 0) sred[wv] = s;
    __syncthreads();
    float inv = 1.f / (sred[0] + sred[1] + sred[2] + sred[3]);

    const float* pb = p + b * NKEYS + n0;
    float pw[RPC];
    #pragma unroll
    for (int r = 0; r < RPC; ++r) pw[r] = pb[r];    // uniform -> scalar regs
    const float2* vb = (const float2*)(V + ((long)b * NKEYS + n0) * D);
    float2 acc = {0.f, 0.f};
    #pragma unroll 8
    for (int r = 0; r < RPC; ++r) {
        float2 vv = vb[r * (D / 2) + tid];
        acc.x = fmaf(pw[r], vv.x, acc.x);
        acc.y = fmaf(pw[r], vv.y, acc.y);
    }
    acc.x *= inv; acc.y *= inv;
    atomicAdd(&out[b * D + 2 * tid],     acc.x);
    atomicAdd(&out[b * D + 2 * tid + 1], acc.y);
    if (tid < RPC) wout[b * NKEYS + n0 + tid] = pw[tid] * inv;
}

extern "C" void kernel_launch(void* const* d_in, const int* in_sizes, int n_in,
                              void* d_out, int out_size, void* d_ws, size_t ws_size,
                              hipStream_t stream) {
    const float* Q  = (const float*)d_in[0];
    const float* K  = (const float*)d_in[1];
    const float* V  = (const float*)d_in[2];
    const float* Wk = (const float*)d_in[3];
    const float* bk = (const float*)d_in[4];
    const float* Wq = (const float*)d_in[5];
    const float* bq = (const float*)d_in[6];
    const float* Wh = (const float*)d_in[7];
    const float* bh = (const float*)d_in[8];

    float* out  = (float*)d_out;               // [32, 512]
    float* wout = out + NB * D;                // [32, 2048]

    float* ws    = (float*)d_ws;
    float* qacc  = ws;                         // 32
    float* cbias = ws + 64;                    // 1
    float* wkh   = ws + 128;                   // 512
    float* pbuf  = ws + 640;                   // 65536 (16B aligned)

    hipMemsetAsync(ws, 0, 128 * sizeof(float), stream);   // qacc (+cbias slot)
    prep_kernel<<<D + 1, 256, 0, stream>>>(Wk, Wq, Wh, Q, bk, bq, bh, wkh, qacc, cbias);
    energy_kernel<<<(NB * NKEYS) / 4, 256, 0, stream>>>(K, wkh, qacc, cbias, pbuf, out);
    weightedv_kernel<<<NB * NCHUNK, 256, 0, stream>>>(V, pbuf, out, wout);
}